// Round 1
// 392.895 us; speedup vs baseline: 1.0295x; 1.0295x over previous
//
#include <hip/hip_runtime.h>
#include <math.h>

// Problem constants (fixed by reference)
#define NN 50000
#define NE 800000
#define F_IN 128
#define F_HID 256
#define NG 64
#define SCAN_B 256
#define SCAN_NB ((NN + SCAN_B - 1) / SCAN_B)   // 196

typedef __bf16 bf16x8 __attribute__((ext_vector_type(8)));
typedef float f32x4 __attribute__((ext_vector_type(4)));
typedef unsigned short u16x8 __attribute__((ext_vector_type(8)));   // 16 B

static __device__ __forceinline__ unsigned short f2bf(float f) {
    union { float f; unsigned u; } v; v.f = f;
    unsigned r = v.u + 0x7fff + ((v.u >> 16) & 1);   // RNE
    return (unsigned short)(r >> 16);
}
static __device__ __forceinline__ float bf2f(unsigned short u) {
    union { unsigned u; float f; } v; v.u = ((unsigned)u) << 16;
    return v.f;
}

// ------- bf16 MFMA GEMM + fused attention dots ------------------------------
// C16[M,256] = A[M,K] @ Wt[256,K]^T (fp32 acc, bf16 out). AF32: A is fp32 and
// is converted to bf16 in-register during staging (fuses the cvt pass).
// K-loop software-pipelined: next iter's global tiles prefetch into registers
// during the MFMA section. Epilogue fuses as/ad attention dots.
template <int K, bool AF32>
__global__ __launch_bounds__(256)
void gemm_mfma(const void* __restrict__ Ap, const ushort* __restrict__ Wt,
               ushort* __restrict__ C16, const float* __restrict__ a_s,
               const float* __restrict__ a_d, float* __restrict__ as_out,
               float* __restrict__ ad_out, int M) {
    const ushort* A16 = (const ushort*)Ap;
    const float* A32 = (const float*)Ap;
    __shared__ ushort As[128 * 40];
    __shared__ ushort Bs[128 * 40];
    const int t = threadIdx.x;
    const int bm = blockIdx.x * 128, bn = blockIdx.y * 128;
    const int wv = t >> 6, lane = t & 63;
    const int wm = (wv & 1) * 64, wn = (wv >> 1) * 64;
    const int lrow = lane & 15, quad = lane >> 4;
    const int srow = t >> 2;            // 0..63 staging row
    const int skp = (t & 3) << 3;       // 0,8,16,24 (element offset, 8 each)

    f32x4 acc[4][4];
    #pragma unroll
    for (int i = 0; i < 4; ++i)
        #pragma unroll
        for (int j = 0; j < 4; ++j)
            #pragma unroll
            for (int r = 0; r < 4; ++r) acc[i][j][r] = 0.f;

    const int r0 = bm + srow, r1 = bm + srow + 64;
    const int rb0 = bn + srow, rb1 = bn + srow + 64;

    auto load_a = [&](int k0, u16x8& a0, u16x8& a1) {
        a0 = (u16x8)(0); a1 = (u16x8)(0);
        if (AF32) {
            if (r0 < M) {
                const float* p = A32 + (size_t)r0 * K + k0 + skp;
                float4 f0 = *(const float4*)p, f1 = *(const float4*)(p + 4);
                a0[0]=f2bf(f0.x); a0[1]=f2bf(f0.y); a0[2]=f2bf(f0.z); a0[3]=f2bf(f0.w);
                a0[4]=f2bf(f1.x); a0[5]=f2bf(f1.y); a0[6]=f2bf(f1.z); a0[7]=f2bf(f1.w);
            }
            if (r1 < M) {
                const float* p = A32 + (size_t)r1 * K + k0 + skp;
                float4 f0 = *(const float4*)p, f1 = *(const float4*)(p + 4);
                a1[0]=f2bf(f0.x); a1[1]=f2bf(f0.y); a1[2]=f2bf(f0.z); a1[3]=f2bf(f0.w);
                a1[4]=f2bf(f1.x); a1[5]=f2bf(f1.y); a1[6]=f2bf(f1.z); a1[7]=f2bf(f1.w);
            }
        } else {
            if (r0 < M) a0 = *(const u16x8*)(A16 + (size_t)r0 * K + k0 + skp);
            if (r1 < M) a1 = *(const u16x8*)(A16 + (size_t)r1 * K + k0 + skp);
        }
    };

    u16x8 a0, a1, b0, b1;
    load_a(0, a0, a1);
    b0 = *(const u16x8*)(Wt + (size_t)rb0 * K + skp);
    b1 = *(const u16x8*)(Wt + (size_t)rb1 * K + skp);

    for (int k0 = 0; k0 < K; k0 += 32) {
        __syncthreads();   // previous iter's LDS reads complete
        *(u16x8*)(As + srow * 40 + skp) = a0;
        *(u16x8*)(As + (srow + 64) * 40 + skp) = a1;
        *(u16x8*)(Bs + srow * 40 + skp) = b0;
        *(u16x8*)(Bs + (srow + 64) * 40 + skp) = b1;
        __syncthreads();
        bool more = (k0 + 32) < K;
        u16x8 na0, na1, nb0, nb1;
        if (more) {        // prefetch overlaps the MFMA section below
            load_a(k0 + 32, na0, na1);
            nb0 = *(const u16x8*)(Wt + (size_t)rb0 * K + k0 + 32 + skp);
            nb1 = *(const u16x8*)(Wt + (size_t)rb1 * K + k0 + 32 + skp);
        }
        bf16x8 af[4], bf_[4];
        #pragma unroll
        for (int i = 0; i < 4; ++i)
            af[i] = *(const bf16x8*)(As + (wm + i * 16 + lrow) * 40 + quad * 8);
        #pragma unroll
        for (int j = 0; j < 4; ++j)
            bf_[j] = *(const bf16x8*)(Bs + (wn + j * 16 + lrow) * 40 + quad * 8);
        #pragma unroll
        for (int i = 0; i < 4; ++i)
            #pragma unroll
            for (int j = 0; j < 4; ++j)
                acc[i][j] = __builtin_amdgcn_mfma_f32_16x16x32_bf16(
                    af[i], bf_[j], acc[i][j], 0, 0, 0);
        if (more) { a0 = na0; a1 = na1; b0 = nb0; b1 = nb1; }
    }
    // fused attention dots: this lane covers cols wn+j*16+lrow
    float asf[4], adf[4];
    #pragma unroll
    for (int j = 0; j < 4; ++j) {
        asf[j] = a_s[bn + wn + j * 16 + lrow];
        adf[j] = a_d[bn + wn + j * 16 + lrow];
    }
    // epilogue: C/D layout col=lane&15, row=quad*4+reg -> bf16 store + dots
    #pragma unroll
    for (int i = 0; i < 4; ++i) {
        int gm0 = bm + wm + i * 16 + quad * 4;
        #pragma unroll
        for (int r = 0; r < 4; ++r) {
            float ps = 0.f, pd = 0.f;
            #pragma unroll
            for (int j = 0; j < 4; ++j) {
                ps += acc[i][j][r] * asf[j];
                pd += acc[i][j][r] * adf[j];
            }
            #pragma unroll
            for (int off = 8; off; off >>= 1) {
                ps += __shfl_xor(ps, off);
                pd += __shfl_xor(pd, off);
            }
            if (lrow == 0 && gm0 + r < M) {
                atomicAdd(&as_out[gm0 + r], ps);
                atomicAdd(&ad_out[gm0 + r], pd);
            }
        }
        #pragma unroll
        for (int j = 0; j < 4; ++j) {
            int gn = bn + wn + j * 16 + lrow;
            #pragma unroll
            for (int r = 0; r < 4; ++r)
                if (gm0 + r < M) C16[(size_t)(gm0 + r) * 256 + gn] = f2bf(acc[i][j][r]);
        }
    }
}

// W1[128,256] and W2[256,256] fp32 -> Wt bf16 [256,K] transposed, one launch
__global__ void cvt_wts(const float* __restrict__ W1, ushort* __restrict__ Wt1,
                        const float* __restrict__ W2, ushort* __restrict__ Wt2) {
    int idx = blockIdx.x * blockDim.x + threadIdx.x;
    if (idx < 256 * F_IN) {
        int n = idx / F_IN, k = idx - n * F_IN;
        Wt1[idx] = f2bf(W1[(size_t)k * 256 + n]);
    } else if (idx < 256 * F_IN + 256 * F_HID) {
        int i2 = idx - 256 * F_IN;
        int n = i2 / F_HID, k = i2 - n * F_HID;
        Wt2[i2] = f2bf(W2[(size_t)k * 256 + n]);
    }
}

// ---------------- CSR build (counts pre-zeroed by memset) ----------------
__global__ void hist_kernel(const int* __restrict__ dst, int* __restrict__ counts,
                            int E, int n) {
    int e = blockIdx.x * blockDim.x + threadIdx.x;
    if (e < E) atomicAdd(&counts[dst[e]], 1);
    else if (e < E + n) atomicAdd(&counts[e - E], 1);   // self-loop
}

// ---- 3-phase parallel exclusive scan of counts[0..n) -> offsets[0..n] ----
__global__ __launch_bounds__(SCAN_B)
void scan_partials(const int* __restrict__ counts, int* __restrict__ block_sums, int n) {
    __shared__ int ws_[SCAN_B / 64];
    int i = blockIdx.x * SCAN_B + threadIdx.x;
    int v = (i < n) ? counts[i] : 0;
    #pragma unroll
    for (int off = 32; off; off >>= 1) v += __shfl_xor(v, off);
    int wid = threadIdx.x >> 6;
    if ((threadIdx.x & 63) == 0) ws_[wid] = v;
    __syncthreads();
    if (threadIdx.x == 0) {
        int s = 0;
        #pragma unroll
        for (int w = 0; w < SCAN_B / 64; ++w) s += ws_[w];
        block_sums[blockIdx.x] = s;
    }
}

__global__ __launch_bounds__(256)
void scan_block_sums(int* __restrict__ block_sums, int* __restrict__ block_offs,
                     int* __restrict__ offsets_end, int nb, int n) {
    __shared__ int s[256];
    int tid = threadIdx.x;
    int v = (tid < nb) ? block_sums[tid] : 0;
    s[tid] = v;
    __syncthreads();
    for (int d = 1; d < 256; d <<= 1) {
        int t = (tid >= d) ? s[tid - d] : 0;
        __syncthreads();
        s[tid] += t;
        __syncthreads();
    }
    if (tid < nb) block_offs[tid] = s[tid] - v;   // exclusive
    if (tid == 255) *offsets_end = s[255];        // offsets[n] = total
}

__global__ __launch_bounds__(SCAN_B)
void scan_final(const int* __restrict__ counts, const int* __restrict__ block_offs,
                int* __restrict__ offsets, int* __restrict__ cursor, int n) {
    __shared__ int s[SCAN_B];
    int tid = threadIdx.x;
    int i = blockIdx.x * SCAN_B + tid;
    int c = (i < n) ? counts[i] : 0;
    s[tid] = c;
    __syncthreads();
    for (int d = 1; d < SCAN_B; d <<= 1) {
        int t = (tid >= d) ? s[tid - d] : 0;
        __syncthreads();
        s[tid] += t;
        __syncthreads();
    }
    if (i < n) {
        int o = block_offs[blockIdx.x] + s[tid] - c;   // exclusive
        offsets[i] = o;
        cursor[i] = o;
    }
}

__global__ void scatter_kernel(const int* __restrict__ src, const int* __restrict__ dst,
                               int* __restrict__ cursor, int* __restrict__ src_sorted,
                               int E, int n) {
    int e = blockIdx.x * blockDim.x + threadIdx.x;
    if (e < E) {
        int d = dst[e];
        int pos = atomicAdd(&cursor[d], 1);
        src_sorted[pos] = src[e];
    } else if (e < E + n) {
        int i = e - E;
        int pos = atomicAdd(&cursor[i], 1);
        src_sorted[pos] = i;
    }
}

// ---------------- GAT aggregation: one wave per dst node ----------------
// Register-resident logits (deg<=64 fast path); pass 3 unrolled x4:
// 8 edges/iter, 4 independent 16 B gathers in flight per lane (latency
// hiding — agg is gather-latency-bound, not BW-bound: L2-side 6.5 TB/s
// vs 34.5 ceiling, fabric 0.36 TB/s/XCD vs ~1). Invalid slots get w=0
// and a harmless cache-hot re-load (branch-free main loop).
template <bool ACT, bool BF16OUT>
__global__ __launch_bounds__(256)
void agg_kernel(const ushort* __restrict__ h, const float* __restrict__ as,
                const float* __restrict__ ad, const int* __restrict__ offsets,
                const int* __restrict__ src_sorted, const float* __restrict__ bias,
                float* __restrict__ out, ushort* __restrict__ out16, int n) {
    int wv = (int)((blockIdx.x * blockDim.x + threadIdx.x) >> 6);
    int lane = threadIdx.x & 63;
    if (wv >= n) return;
    int start = offsets[wv], end = offsets[wv + 1];
    int deg = end - start;
    float adn = ad[wv];

    int s_lane = 0;
    float e_lane = -INFINITY;
    if (lane < deg) {
        s_lane = src_sorted[start + lane];
        float e = as[s_lane] + adn;
        e_lane = e > 0.f ? e : 0.2f * e;
    }
    float m = e_lane;
    for (int j = start + 64 + lane; j < end; j += 64) {   // deg>64 tail (rare)
        int s = src_sorted[j];
        float e = as[s] + adn;
        e = e > 0.f ? e : 0.2f * e;
        m = fmaxf(m, e);
    }
    #pragma unroll
    for (int off = 32; off; off >>= 1) m = fmaxf(m, __shfl_xor(m, off));
    float p_lane = __expf(e_lane - m);                    // 0 for inactive lanes
    float denom = p_lane;
    for (int j = start + 64 + lane; j < end; j += 64) {   // rare
        int s = src_sorted[j];
        float e = as[s] + adn;
        e = e > 0.f ? e : 0.2f * e;
        denom += __expf(e - m);
    }
    #pragma unroll
    for (int off = 32; off; off >>= 1) denom += __shfl_xor(denom, off);
    float inv = 1.f / denom;
    p_lane *= inv;                                        // normalized weight

    // pass 3: lanes 0-31 -> even edges, lanes 32-63 -> odd edges; 16 B/lane,
    // 4 rows (8 edges) per iteration for MLP.
    const int half = lane >> 5;
    const int hl = lane & 31;
    const ushort* hrow = h + hl * 8;
    float acc[8] = {0.f, 0.f, 0.f, 0.f, 0.f, 0.f, 0.f, 0.f};
    const int degc = min(deg, 64);
    for (int j0 = 0; j0 < degc; j0 += 8) {
        int ja = j0 + half, jb = j0 + 2 + half, jc = j0 + 4 + half, jd = j0 + 6 + half;
        // indices stay <= 63 (degc <= 64); invalid slots read a live lane's
        // (s,p) but get w forced to 0 -> contributes nothing.
        float wa = __shfl(p_lane, ja); int sa = __shfl(s_lane, ja);
        float wb = __shfl(p_lane, jb); int sb = __shfl(s_lane, jb);
        float wc = __shfl(p_lane, jc); int sc = __shfl(s_lane, jc);
        float wd = __shfl(p_lane, jd); int sd = __shfl(s_lane, jd);
        wa = (ja < degc) ? wa : 0.f;
        wb = (jb < degc) ? wb : 0.f;
        wc = (jc < degc) ? wc : 0.f;
        wd = (jd < degc) ? wd : 0.f;
        u16x8 ra = *(const u16x8*)(hrow + (size_t)sa * 256);
        u16x8 rb = *(const u16x8*)(hrow + (size_t)sb * 256);
        u16x8 rc = *(const u16x8*)(hrow + (size_t)sc * 256);
        u16x8 rd = *(const u16x8*)(hrow + (size_t)sd * 256);
        #pragma unroll
        for (int k = 0; k < 8; ++k) acc[k] += wa * bf2f(ra[k]);
        #pragma unroll
        for (int k = 0; k < 8; ++k) acc[k] += wb * bf2f(rb[k]);
        #pragma unroll
        for (int k = 0; k < 8; ++k) acc[k] += wc * bf2f(rc[k]);
        #pragma unroll
        for (int k = 0; k < 8; ++k) acc[k] += wd * bf2f(rd[k]);
    }
    if (deg > 64) {                                       // rare tail
        for (int j0 = 64; j0 < deg; j0 += 2) {
            int myj = j0 + half;
            if (myj < deg) {
                int s = src_sorted[start + myj];
                float e = as[s] + adn;
                e = e > 0.f ? e : 0.2f * e;
                float w = __expf(e - m) * inv;
                u16x8 row = *(const u16x8*)(hrow + (size_t)s * 256);
                #pragma unroll
                for (int k = 0; k < 8; ++k) acc[k] += w * bf2f(row[k]);
            }
        }
    }
    #pragma unroll
    for (int k = 0; k < 8; ++k) acc[k] += __shfl_xor(acc[k], 32);
    if (half == 0) {
        const float4* b4 = (const float4*)bias;
        float4 b0 = b4[hl * 2], b1 = b4[hl * 2 + 1];
        float v[8];
        v[0] = acc[0] + b0.x; v[1] = acc[1] + b0.y; v[2] = acc[2] + b0.z; v[3] = acc[3] + b0.w;
        v[4] = acc[4] + b1.x; v[5] = acc[5] + b1.y; v[6] = acc[6] + b1.z; v[7] = acc[7] + b1.w;
        if (ACT) {
            #pragma unroll
            for (int k = 0; k < 8; ++k) v[k] = v[k] > 0.f ? v[k] : 0.01f * v[k];
        }
        if (BF16OUT) {
            u16x8 o;
            #pragma unroll
            for (int k = 0; k < 8; ++k) o[k] = f2bf(v[k]);
            *(u16x8*)(out16 + (size_t)wv * 256 + hl * 8) = o;
        } else {
            float4 o0 = make_float4(v[0], v[1], v[2], v[3]);
            float4 o1 = make_float4(v[4], v[5], v[6], v[7]);
            float4* op = (float4*)(out + (size_t)wv * 256);
            op[hl * 2] = o0;
            op[hl * 2 + 1] = o1;
        }
    }
}

// ---------------- graph pooling (batch sorted; graph_emb pre-zeroed) -------
__global__ __launch_bounds__(256)
void pool_kernel(const float* __restrict__ node_emb, const int* __restrict__ batch,
                 float* __restrict__ graph_emb, int n) {
    int f = threadIdx.x;
    int chunk = (n + gridDim.x - 1) / gridDim.x;
    int i0 = blockIdx.x * chunk;
    int i1 = min(i0 + chunk, n);
    if (i0 >= i1) return;
    float acc = 0.f;
    int cur = batch[i0];
    for (int i = i0; i < i1; ++i) {
        int g = batch[i];
        if (g != cur) {
            atomicAdd(&graph_emb[(size_t)cur * 256 + f], acc);
            acc = 0.f; cur = g;
        }
        acc += node_emb[(size_t)i * 256 + f];
    }
    atomicAdd(&graph_emb[(size_t)cur * 256 + f], acc);
}

static inline char* align_up(char* p, size_t a) {
    return (char*)(((uintptr_t)p + a - 1) & ~(uintptr_t)(a - 1));
}

extern "C" void kernel_launch(void* const* d_in, const int* in_sizes, int n_in,
                              void* d_out, int out_size, void* d_ws, size_t ws_size,
                              hipStream_t stream) {
    const float* x     = (const float*)d_in[0];
    const int* eidx    = (const int*)d_in[1];   // [2, E]: row0=src, row1=dst
    const int* batch   = (const int*)d_in[2];
    const float* W1    = (const float*)d_in[3];
    const float* a_s1  = (const float*)d_in[4];
    const float* a_d1  = (const float*)d_in[5];
    const float* b1    = (const float*)d_in[6];
    const float* W2    = (const float*)d_in[7];
    const float* a_s2  = (const float*)d_in[8];
    const float* a_d2  = (const float*)d_in[9];
    const float* b2    = (const float*)d_in[10];

    float* node_emb  = (float*)d_out;                       // [NN, 256]
    float* graph_emb = node_emb + (size_t)NN * 256;         // [NG, 256]

    char* ws = (char*)d_ws;
    ushort* h16  = (ushort*)ws;  ws += (size_t)NN * 256 * sizeof(ushort);  // gemm out (bf16)
    ws = align_up(ws, 256);
    ushort* z16  = (ushort*)ws;  ws += (size_t)NN * 256 * sizeof(ushort);  // agg1 out (bf16)
    ws = align_up(ws, 256);
    ushort* wt1  = (ushort*)ws;  ws += (size_t)256 * F_IN * sizeof(ushort);
    ws = align_up(ws, 256);
    ushort* wt2  = (ushort*)ws;  ws += (size_t)256 * F_HID * sizeof(ushort);
    ws = align_up(ws, 256);
    float* as_buf = (float*)ws;  ws += (size_t)NN * sizeof(float);
    float* ad_buf = (float*)ws;  ws += (size_t)NN * sizeof(float);   // contiguous w/ as_buf
    int* counts   = (int*)ws;    ws += (size_t)NN * sizeof(int);
    int* offsets  = (int*)ws;    ws += (size_t)(NN + 1) * sizeof(int);
    ws = align_up(ws, 256);
    int* cursor   = (int*)ws;    ws += (size_t)NN * sizeof(int);
    int* bsum     = (int*)ws;    ws += (size_t)SCAN_NB * sizeof(int);
    int* boff     = (int*)ws;    ws += (size_t)SCAN_NB * sizeof(int);
    ws = align_up(ws, 256);
    int* src_sorted = (int*)ws;  ws += (size_t)(NE + NN) * sizeof(int);

    const int* e_src = eidx;
    const int* e_dst = eidx + NE;

    dim3 gemm_grid((NN + 127) / 128, 2);
    int node_waves_blocks = (NN + 3) / 4;   // 4 waves per 256-thread block

    // ---- CSR build (shared by both layers) ----
    hipMemsetAsync(counts, 0, (size_t)NN * sizeof(int), stream);
    hist_kernel<<<(NE + NN + 255) / 256, 256, 0, stream>>>(e_dst, counts, NE, NN);
    scan_partials<<<SCAN_NB, SCAN_B, 0, stream>>>(counts, bsum, NN);
    scan_block_sums<<<1, 256, 0, stream>>>(bsum, boff, offsets + NN, SCAN_NB, NN);
    scan_final<<<SCAN_NB, SCAN_B, 0, stream>>>(counts, boff, offsets, cursor, NN);
    scatter_kernel<<<(NE + NN + 255) / 256, 256, 0, stream>>>(e_src, e_dst, cursor, src_sorted, NE, NN);

    // ---- weight conversions (one launch) ----
    cvt_wts<<<(256 * (F_IN + F_HID) + 255) / 256, 256, 0, stream>>>(W1, wt1, W2, wt2);

    // ---- layer 1 (A = fp32 x, converted in gemm) ----
    hipMemsetAsync(as_buf, 0, (size_t)2 * NN * sizeof(float), stream);
    gemm_mfma<F_IN, true><<<gemm_grid, 256, 0, stream>>>(x, wt1, h16, a_s1, a_d1, as_buf, ad_buf, NN);
    agg_kernel<true, true><<<node_waves_blocks, 256, 0, stream>>>(h16, as_buf, ad_buf, offsets,
                                                                  src_sorted, b1, nullptr, z16, NN);
    // ---- layer 2 ----
    hipMemsetAsync(as_buf, 0, (size_t)2 * NN * sizeof(float), stream);
    gemm_mfma<F_HID, false><<<gemm_grid, 256, 0, stream>>>(z16, wt2, h16, a_s2, a_d2, as_buf, ad_buf, NN);
    agg_kernel<false, false><<<node_waves_blocks, 256, 0, stream>>>(h16, as_buf, ad_buf, offsets,
                                                                    src_sorted, b2, node_emb, nullptr, NN);
    // ---- pool ----
    hipMemsetAsync(graph_emb, 0, (size_t)NG * 256 * sizeof(float), stream);
    pool_kernel<<<1024, 256, 0, stream>>>(node_emb, batch, graph_emb, NN);
}

// Round 2
// 376.137 us; speedup vs baseline: 1.0754x; 1.0446x over previous
//
#include <hip/hip_runtime.h>
#include <math.h>

// Problem constants (fixed by reference)
#define NN 50000
#define NE 800000
#define F_IN 128
#define F_HID 256
#define NG 64
#define SCAN_B 256
#define SCAN_NB ((NN + SCAN_B - 1) / SCAN_B)   // 196
#define NPART 8          // CSR build partitions (== XCD count)
#define CSR_CHUNKS 128   // blocks per partition

typedef __bf16 bf16x8 __attribute__((ext_vector_type(8)));
typedef float f32x4 __attribute__((ext_vector_type(4)));
typedef unsigned short u16x8 __attribute__((ext_vector_type(8)));   // 16 B

static __device__ __forceinline__ unsigned short f2bf(float f) {
    union { float f; unsigned u; } v; v.f = f;
    unsigned r = v.u + 0x7fff + ((v.u >> 16) & 1);   // RNE
    return (unsigned short)(r >> 16);
}
static __device__ __forceinline__ float bf2f(unsigned short u) {
    union { unsigned u; float f; } v; v.u = ((unsigned)u) << 16;
    return v.f;
}

// ------- bf16 MFMA GEMM + fused attention dots ------------------------------
// C16[M,256] = A[M,K] @ Wt[256,K]^T (fp32 acc, bf16 out). AF32: A is fp32 and
// is converted to bf16 in-register during staging (fuses the cvt pass).
// K-loop software-pipelined: next iter's global tiles prefetch into registers
// during the MFMA section. Epilogue fuses as/ad attention dots.
template <int K, bool AF32>
__global__ __launch_bounds__(256)
void gemm_mfma(const void* __restrict__ Ap, const ushort* __restrict__ Wt,
               ushort* __restrict__ C16, const float* __restrict__ a_s,
               const float* __restrict__ a_d, float* __restrict__ as_out,
               float* __restrict__ ad_out, int M) {
    const ushort* A16 = (const ushort*)Ap;
    const float* A32 = (const float*)Ap;
    __shared__ ushort As[128 * 40];
    __shared__ ushort Bs[128 * 40];
    const int t = threadIdx.x;
    const int bm = blockIdx.x * 128, bn = blockIdx.y * 128;
    const int wv = t >> 6, lane = t & 63;
    const int wm = (wv & 1) * 64, wn = (wv >> 1) * 64;
    const int lrow = lane & 15, quad = lane >> 4;
    const int srow = t >> 2;            // 0..63 staging row
    const int skp = (t & 3) << 3;       // 0,8,16,24 (element offset, 8 each)

    f32x4 acc[4][4];
    #pragma unroll
    for (int i = 0; i < 4; ++i)
        #pragma unroll
        for (int j = 0; j < 4; ++j)
            #pragma unroll
            for (int r = 0; r < 4; ++r) acc[i][j][r] = 0.f;

    const int r0 = bm + srow, r1 = bm + srow + 64;
    const int rb0 = bn + srow, rb1 = bn + srow + 64;

    auto load_a = [&](int k0, u16x8& a0, u16x8& a1) {
        a0 = (u16x8)(0); a1 = (u16x8)(0);
        if (AF32) {
            if (r0 < M) {
                const float* p = A32 + (size_t)r0 * K + k0 + skp;
                float4 f0 = *(const float4*)p, f1 = *(const float4*)(p + 4);
                a0[0]=f2bf(f0.x); a0[1]=f2bf(f0.y); a0[2]=f2bf(f0.z); a0[3]=f2bf(f0.w);
                a0[4]=f2bf(f1.x); a0[5]=f2bf(f1.y); a0[6]=f2bf(f1.z); a0[7]=f2bf(f1.w);
            }
            if (r1 < M) {
                const float* p = A32 + (size_t)r1 * K + k0 + skp;
                float4 f0 = *(const float4*)p, f1 = *(const float4*)(p + 4);
                a1[0]=f2bf(f0.x); a1[1]=f2bf(f0.y); a1[2]=f2bf(f0.z); a1[3]=f2bf(f0.w);
                a1[4]=f2bf(f1.x); a1[5]=f2bf(f1.y); a1[6]=f2bf(f1.z); a1[7]=f2bf(f1.w);
            }
        } else {
            if (r0 < M) a0 = *(const u16x8*)(A16 + (size_t)r0 * K + k0 + skp);
            if (r1 < M) a1 = *(const u16x8*)(A16 + (size_t)r1 * K + k0 + skp);
        }
    };

    u16x8 a0, a1, b0, b1;
    load_a(0, a0, a1);
    b0 = *(const u16x8*)(Wt + (size_t)rb0 * K + skp);
    b1 = *(const u16x8*)(Wt + (size_t)rb1 * K + skp);

    for (int k0 = 0; k0 < K; k0 += 32) {
        __syncthreads();   // previous iter's LDS reads complete
        *(u16x8*)(As + srow * 40 + skp) = a0;
        *(u16x8*)(As + (srow + 64) * 40 + skp) = a1;
        *(u16x8*)(Bs + srow * 40 + skp) = b0;
        *(u16x8*)(Bs + (srow + 64) * 40 + skp) = b1;
        __syncthreads();
        bool more = (k0 + 32) < K;
        u16x8 na0, na1, nb0, nb1;
        if (more) {        // prefetch overlaps the MFMA section below
            load_a(k0 + 32, na0, na1);
            nb0 = *(const u16x8*)(Wt + (size_t)rb0 * K + k0 + 32 + skp);
            nb1 = *(const u16x8*)(Wt + (size_t)rb1 * K + k0 + 32 + skp);
        }
        bf16x8 af[4], bf_[4];
        #pragma unroll
        for (int i = 0; i < 4; ++i)
            af[i] = *(const bf16x8*)(As + (wm + i * 16 + lrow) * 40 + quad * 8);
        #pragma unroll
        for (int j = 0; j < 4; ++j)
            bf_[j] = *(const bf16x8*)(Bs + (wn + j * 16 + lrow) * 40 + quad * 8);
        #pragma unroll
        for (int i = 0; i < 4; ++i)
            #pragma unroll
            for (int j = 0; j < 4; ++j)
                acc[i][j] = __builtin_amdgcn_mfma_f32_16x16x32_bf16(
                    af[i], bf_[j], acc[i][j], 0, 0, 0);
        if (more) { a0 = na0; a1 = na1; b0 = nb0; b1 = nb1; }
    }
    // fused attention dots: this lane covers cols wn+j*16+lrow
    float asf[4], adf[4];
    #pragma unroll
    for (int j = 0; j < 4; ++j) {
        asf[j] = a_s[bn + wn + j * 16 + lrow];
        adf[j] = a_d[bn + wn + j * 16 + lrow];
    }
    // epilogue: C/D layout col=lane&15, row=quad*4+reg -> bf16 store + dots
    #pragma unroll
    for (int i = 0; i < 4; ++i) {
        int gm0 = bm + wm + i * 16 + quad * 4;
        #pragma unroll
        for (int r = 0; r < 4; ++r) {
            float ps = 0.f, pd = 0.f;
            #pragma unroll
            for (int j = 0; j < 4; ++j) {
                ps += acc[i][j][r] * asf[j];
                pd += acc[i][j][r] * adf[j];
            }
            #pragma unroll
            for (int off = 8; off; off >>= 1) {
                ps += __shfl_xor(ps, off);
                pd += __shfl_xor(pd, off);
            }
            if (lrow == 0 && gm0 + r < M) {
                atomicAdd(&as_out[gm0 + r], ps);
                atomicAdd(&ad_out[gm0 + r], pd);
            }
        }
        #pragma unroll
        for (int j = 0; j < 4; ++j) {
            int gn = bn + wn + j * 16 + lrow;
            #pragma unroll
            for (int r = 0; r < 4; ++r)
                if (gm0 + r < M) C16[(size_t)(gm0 + r) * 256 + gn] = f2bf(acc[i][j][r]);
        }
    }
}

// W1[128,256] and W2[256,256] fp32 -> Wt bf16 [256,K] transposed, one launch
__global__ void cvt_wts(const float* __restrict__ W1, ushort* __restrict__ Wt1,
                        const float* __restrict__ W2, ushort* __restrict__ Wt2) {
    int idx = blockIdx.x * blockDim.x + threadIdx.x;
    if (idx < 256 * F_IN) {
        int n = idx / F_IN, k = idx - n * F_IN;
        Wt1[idx] = f2bf(W1[(size_t)k * 256 + n]);
    } else if (idx < 256 * F_IN + 256 * F_HID) {
        int i2 = idx - 256 * F_IN;
        int n = i2 / F_HID, k = i2 - n * F_HID;
        Wt2[i2] = f2bf(W2[(size_t)k * 256 + n]);
    }
}

// ---------------- CSR build (counts pre-zeroed by memset) ----------------
// Partitioned by dst range with XCD affinity: p = blockIdx.x & 7 lands on
// XCD p (round-robin dispatch), partition pd = d*NPART/NN. Each partition's
// atomics + scattered writes touch only a ~425 KB slice from ONE XCD's L2:
// lines are merged locally and evicted once (was: 64 B HBM write per 4 B
// scatter, 55 MB WRITE_SIZE, cross-XCD line ping-pong). Cost: dst/src
// streams re-read NPART x (coalesced, ~9 us).
__global__ __launch_bounds__(256)
void hist_part(const int* __restrict__ dst, int* __restrict__ counts,
               int E, int n) {
    const int p = blockIdx.x & (NPART - 1);
    const int c = blockIdx.x >> 3;
    const int T = E + n;
    const int chunk = (T + CSR_CHUNKS - 1) / CSR_CHUNKS;
    const int i0 = c * chunk;
    const int i1 = min(i0 + chunk, T);
    for (int i = i0 + (int)threadIdx.x; i < i1; i += 256) {
        int d = (i < E) ? dst[i] : (i - E);     // self-loop for i >= E
        int pd = (d * NPART) / NN;              // magic-mul division
        if (pd == p) atomicAdd(&counts[d], 1);
    }
}

// ---- 3-phase parallel exclusive scan of counts[0..n) -> offsets[0..n] ----
__global__ __launch_bounds__(SCAN_B)
void scan_partials(const int* __restrict__ counts, int* __restrict__ block_sums, int n) {
    __shared__ int ws_[SCAN_B / 64];
    int i = blockIdx.x * SCAN_B + threadIdx.x;
    int v = (i < n) ? counts[i] : 0;
    #pragma unroll
    for (int off = 32; off; off >>= 1) v += __shfl_xor(v, off);
    int wid = threadIdx.x >> 6;
    if ((threadIdx.x & 63) == 0) ws_[wid] = v;
    __syncthreads();
    if (threadIdx.x == 0) {
        int s = 0;
        #pragma unroll
        for (int w = 0; w < SCAN_B / 64; ++w) s += ws_[w];
        block_sums[blockIdx.x] = s;
    }
}

__global__ __launch_bounds__(256)
void scan_block_sums(int* __restrict__ block_sums, int* __restrict__ block_offs,
                     int* __restrict__ offsets_end, int nb, int n) {
    __shared__ int s[256];
    int tid = threadIdx.x;
    int v = (tid < nb) ? block_sums[tid] : 0;
    s[tid] = v;
    __syncthreads();
    for (int d = 1; d < 256; d <<= 1) {
        int t = (tid >= d) ? s[tid - d] : 0;
        __syncthreads();
        s[tid] += t;
        __syncthreads();
    }
    if (tid < nb) block_offs[tid] = s[tid] - v;   // exclusive
    if (tid == 255) *offsets_end = s[255];        // offsets[n] = total
}

__global__ __launch_bounds__(SCAN_B)
void scan_final(const int* __restrict__ counts, const int* __restrict__ block_offs,
                int* __restrict__ offsets, int* __restrict__ cursor, int n) {
    __shared__ int s[SCAN_B];
    int tid = threadIdx.x;
    int i = blockIdx.x * SCAN_B + tid;
    int c = (i < n) ? counts[i] : 0;
    s[tid] = c;
    __syncthreads();
    for (int d = 1; d < SCAN_B; d <<= 1) {
        int t = (tid >= d) ? s[tid - d] : 0;
        __syncthreads();
        s[tid] += t;
        __syncthreads();
    }
    if (i < n) {
        int o = block_offs[blockIdx.x] + s[tid] - c;   // exclusive
        offsets[i] = o;
        cursor[i] = o;
    }
}

__global__ __launch_bounds__(256)
void scatter_part(const int* __restrict__ src, const int* __restrict__ dst,
                  int* __restrict__ cursor, int* __restrict__ src_sorted,
                  int E, int n) {
    const int p = blockIdx.x & (NPART - 1);
    const int c = blockIdx.x >> 3;
    const int T = E + n;
    const int chunk = (T + CSR_CHUNKS - 1) / CSR_CHUNKS;
    const int i0 = c * chunk;
    const int i1 = min(i0 + chunk, T);
    for (int i = i0 + (int)threadIdx.x; i < i1; i += 256) {
        int d = (i < E) ? dst[i] : (i - E);
        int pd = (d * NPART) / NN;
        if (pd == p) {
            int s = (i < E) ? src[i] : d;
            int pos = atomicAdd(&cursor[d], 1);
            src_sorted[pos] = s;
        }
    }
}

// ---------------- GAT aggregation: one wave per dst node ----------------
// Register-resident logits (deg<=64 fast path); pass 3 unrolled x4:
// 8 edges/iter, 4 independent 16 B gathers in flight per lane. Invalid
// slots get w=0 and a harmless cache-hot re-load (branch-free main loop).
template <bool ACT, bool BF16OUT>
__global__ __launch_bounds__(256)
void agg_kernel(const ushort* __restrict__ h, const float* __restrict__ as,
                const float* __restrict__ ad, const int* __restrict__ offsets,
                const int* __restrict__ src_sorted, const float* __restrict__ bias,
                float* __restrict__ out, ushort* __restrict__ out16, int n) {
    int wv = (int)((blockIdx.x * blockDim.x + threadIdx.x) >> 6);
    int lane = threadIdx.x & 63;
    if (wv >= n) return;
    int start = offsets[wv], end = offsets[wv + 1];
    int deg = end - start;
    float adn = ad[wv];

    int s_lane = 0;
    float e_lane = -INFINITY;
    if (lane < deg) {
        s_lane = src_sorted[start + lane];
        float e = as[s_lane] + adn;
        e_lane = e > 0.f ? e : 0.2f * e;
    }
    float m = e_lane;
    for (int j = start + 64 + lane; j < end; j += 64) {   // deg>64 tail (rare)
        int s = src_sorted[j];
        float e = as[s] + adn;
        e = e > 0.f ? e : 0.2f * e;
        m = fmaxf(m, e);
    }
    #pragma unroll
    for (int off = 32; off; off >>= 1) m = fmaxf(m, __shfl_xor(m, off));
    float p_lane = __expf(e_lane - m);                    // 0 for inactive lanes
    float denom = p_lane;
    for (int j = start + 64 + lane; j < end; j += 64) {   // rare
        int s = src_sorted[j];
        float e = as[s] + adn;
        e = e > 0.f ? e : 0.2f * e;
        denom += __expf(e - m);
    }
    #pragma unroll
    for (int off = 32; off; off >>= 1) denom += __shfl_xor(denom, off);
    float inv = 1.f / denom;
    p_lane *= inv;                                        // normalized weight

    // pass 3: lanes 0-31 -> even edges, lanes 32-63 -> odd edges; 16 B/lane,
    // 4 rows (8 edges) per iteration for MLP.
    const int half = lane >> 5;
    const int hl = lane & 31;
    const ushort* hrow = h + hl * 8;
    float acc[8] = {0.f, 0.f, 0.f, 0.f, 0.f, 0.f, 0.f, 0.f};
    const int degc = min(deg, 64);
    for (int j0 = 0; j0 < degc; j0 += 8) {
        int ja = j0 + half, jb = j0 + 2 + half, jc = j0 + 4 + half, jd = j0 + 6 + half;
        // indices stay <= 63 (degc <= 64); invalid slots read a live lane's
        // (s,p) but get w forced to 0 -> contributes nothing.
        float wa = __shfl(p_lane, ja); int sa = __shfl(s_lane, ja);
        float wb = __shfl(p_lane, jb); int sb = __shfl(s_lane, jb);
        float wc = __shfl(p_lane, jc); int sc = __shfl(s_lane, jc);
        float wd = __shfl(p_lane, jd); int sd = __shfl(s_lane, jd);
        wa = (ja < degc) ? wa : 0.f;
        wb = (jb < degc) ? wb : 0.f;
        wc = (jc < degc) ? wc : 0.f;
        wd = (jd < degc) ? wd : 0.f;
        u16x8 ra = *(const u16x8*)(hrow + (size_t)sa * 256);
        u16x8 rb = *(const u16x8*)(hrow + (size_t)sb * 256);
        u16x8 rc = *(const u16x8*)(hrow + (size_t)sc * 256);
        u16x8 rd = *(const u16x8*)(hrow + (size_t)sd * 256);
        #pragma unroll
        for (int k = 0; k < 8; ++k) acc[k] += wa * bf2f(ra[k]);
        #pragma unroll
        for (int k = 0; k < 8; ++k) acc[k] += wb * bf2f(rb[k]);
        #pragma unroll
        for (int k = 0; k < 8; ++k) acc[k] += wc * bf2f(rc[k]);
        #pragma unroll
        for (int k = 0; k < 8; ++k) acc[k] += wd * bf2f(rd[k]);
    }
    if (deg > 64) {                                       // rare tail
        for (int j0 = 64; j0 < deg; j0 += 2) {
            int myj = j0 + half;
            if (myj < deg) {
                int s = src_sorted[start + myj];
                float e = as[s] + adn;
                e = e > 0.f ? e : 0.2f * e;
                float w = __expf(e - m) * inv;
                u16x8 row = *(const u16x8*)(hrow + (size_t)s * 256);
                #pragma unroll
                for (int k = 0; k < 8; ++k) acc[k] += w * bf2f(row[k]);
            }
        }
    }
    #pragma unroll
    for (int k = 0; k < 8; ++k) acc[k] += __shfl_xor(acc[k], 32);
    if (half == 0) {
        const float4* b4 = (const float4*)bias;
        float4 b0 = b4[hl * 2], b1 = b4[hl * 2 + 1];
        float v[8];
        v[0] = acc[0] + b0.x; v[1] = acc[1] + b0.y; v[2] = acc[2] + b0.z; v[3] = acc[3] + b0.w;
        v[4] = acc[4] + b1.x; v[5] = acc[5] + b1.y; v[6] = acc[6] + b1.z; v[7] = acc[7] + b1.w;
        if (ACT) {
            #pragma unroll
            for (int k = 0; k < 8; ++k) v[k] = v[k] > 0.f ? v[k] : 0.01f * v[k];
        }
        if (BF16OUT) {
            u16x8 o;
            #pragma unroll
            for (int k = 0; k < 8; ++k) o[k] = f2bf(v[k]);
            *(u16x8*)(out16 + (size_t)wv * 256 + hl * 8) = o;
        } else {
            float4 o0 = make_float4(v[0], v[1], v[2], v[3]);
            float4 o1 = make_float4(v[4], v[5], v[6], v[7]);
            float4* op = (float4*)(out + (size_t)wv * 256);
            op[hl * 2] = o0;
            op[hl * 2 + 1] = o1;
        }
    }
}

// ---------------- graph pooling (batch sorted; graph_emb pre-zeroed) -------
__global__ __launch_bounds__(256)
void pool_kernel(const float* __restrict__ node_emb, const int* __restrict__ batch,
                 float* __restrict__ graph_emb, int n) {
    int f = threadIdx.x;
    int chunk = (n + gridDim.x - 1) / gridDim.x;
    int i0 = blockIdx.x * chunk;
    int i1 = min(i0 + chunk, n);
    if (i0 >= i1) return;
    float acc = 0.f;
    int cur = batch[i0];
    for (int i = i0; i < i1; ++i) {
        int g = batch[i];
        if (g != cur) {
            atomicAdd(&graph_emb[(size_t)cur * 256 + f], acc);
            acc = 0.f; cur = g;
        }
        acc += node_emb[(size_t)i * 256 + f];
    }
    atomicAdd(&graph_emb[(size_t)cur * 256 + f], acc);
}

static inline char* align_up(char* p, size_t a) {
    return (char*)(((uintptr_t)p + a - 1) & ~(uintptr_t)(a - 1));
}

extern "C" void kernel_launch(void* const* d_in, const int* in_sizes, int n_in,
                              void* d_out, int out_size, void* d_ws, size_t ws_size,
                              hipStream_t stream) {
    const float* x     = (const float*)d_in[0];
    const int* eidx    = (const int*)d_in[1];   // [2, E]: row0=src, row1=dst
    const int* batch   = (const int*)d_in[2];
    const float* W1    = (const float*)d_in[3];
    const float* a_s1  = (const float*)d_in[4];
    const float* a_d1  = (const float*)d_in[5];
    const float* b1    = (const float*)d_in[6];
    const float* W2    = (const float*)d_in[7];
    const float* a_s2  = (const float*)d_in[8];
    const float* a_d2  = (const float*)d_in[9];
    const float* b2    = (const float*)d_in[10];

    float* node_emb  = (float*)d_out;                       // [NN, 256]
    float* graph_emb = node_emb + (size_t)NN * 256;         // [NG, 256]

    char* ws = (char*)d_ws;
    ushort* h16  = (ushort*)ws;  ws += (size_t)NN * 256 * sizeof(ushort);  // gemm out (bf16)
    ws = align_up(ws, 256);
    ushort* z16  = (ushort*)ws;  ws += (size_t)NN * 256 * sizeof(ushort);  // agg1 out (bf16)
    ws = align_up(ws, 256);
    ushort* wt1  = (ushort*)ws;  ws += (size_t)256 * F_IN * sizeof(ushort);
    ws = align_up(ws, 256);
    ushort* wt2  = (ushort*)ws;  ws += (size_t)256 * F_HID * sizeof(ushort);
    ws = align_up(ws, 256);
    float* as_buf = (float*)ws;  ws += (size_t)NN * sizeof(float);
    float* ad_buf = (float*)ws;  ws += (size_t)NN * sizeof(float);   // contiguous w/ as_buf
    int* counts   = (int*)ws;    ws += (size_t)NN * sizeof(int);
    int* offsets  = (int*)ws;    ws += (size_t)(NN + 1) * sizeof(int);
    ws = align_up(ws, 256);
    int* cursor   = (int*)ws;    ws += (size_t)NN * sizeof(int);
    int* bsum     = (int*)ws;    ws += (size_t)SCAN_NB * sizeof(int);
    int* boff     = (int*)ws;    ws += (size_t)SCAN_NB * sizeof(int);
    ws = align_up(ws, 256);
    int* src_sorted = (int*)ws;  ws += (size_t)(NE + NN) * sizeof(int);

    const int* e_src = eidx;
    const int* e_dst = eidx + NE;

    dim3 gemm_grid((NN + 127) / 128, 2);
    int node_waves_blocks = (NN + 3) / 4;   // 4 waves per 256-thread block

    // ---- CSR build (shared by both layers) ----
    hipMemsetAsync(counts, 0, (size_t)NN * sizeof(int), stream);
    hist_part<<<NPART * CSR_CHUNKS, 256, 0, stream>>>(e_dst, counts, NE, NN);
    scan_partials<<<SCAN_NB, SCAN_B, 0, stream>>>(counts, bsum, NN);
    scan_block_sums<<<1, 256, 0, stream>>>(bsum, boff, offsets + NN, SCAN_NB, NN);
    scan_final<<<SCAN_NB, SCAN_B, 0, stream>>>(counts, boff, offsets, cursor, NN);
    scatter_part<<<NPART * CSR_CHUNKS, 256, 0, stream>>>(e_src, e_dst, cursor, src_sorted, NE, NN);

    // ---- weight conversions (one launch) ----
    cvt_wts<<<(256 * (F_IN + F_HID) + 255) / 256, 256, 0, stream>>>(W1, wt1, W2, wt2);

    // ---- layer 1 (A = fp32 x, converted in gemm) ----
    hipMemsetAsync(as_buf, 0, (size_t)2 * NN * sizeof(float), stream);
    gemm_mfma<F_IN, true><<<gemm_grid, 256, 0, stream>>>(x, wt1, h16, a_s1, a_d1, as_buf, ad_buf, NN);
    agg_kernel<true, true><<<node_waves_blocks, 256, 0, stream>>>(h16, as_buf, ad_buf, offsets,
                                                                  src_sorted, b1, nullptr, z16, NN);
    // ---- layer 2 ----
    hipMemsetAsync(as_buf, 0, (size_t)2 * NN * sizeof(float), stream);
    gemm_mfma<F_HID, false><<<gemm_grid, 256, 0, stream>>>(z16, wt2, h16, a_s2, a_d2, as_buf, ad_buf, NN);
    agg_kernel<false, false><<<node_waves_blocks, 256, 0, stream>>>(h16, as_buf, ad_buf, offsets,
                                                                    src_sorted, b2, node_emb, nullptr, NN);
    // ---- pool ----
    hipMemsetAsync(graph_emb, 0, (size_t)NG * 256 * sizeof(float), stream);
    pool_kernel<<<1024, 256, 0, stream>>>(node_emb, batch, graph_emb, NN);
}